// Round 4
// baseline (154.952 us; speedup 1.0000x reference)
//
#include <hip/hip_runtime.h>
#include <math.h>

// Shapes: B=8 S=1024 IN=768 H=8 F=64 ; M=B*S=8192, N=H*F=512, K=768
// Pipeline:
//   conv_w   : W fp32 [768][512] -> WbT bf16 [512][768]          (transpose)
//   gemm_xw  : X fp32 x WbT -> WhT bf16 [bh][f][s]  (MFMA, prefetch-pipelined)
//   src_dst  : srcT/dstT fp32 [bh][s] = WhT . a_src/a_dst ; mask folded into dstT
//   gat_attn : P-scores in MFMA A-frags, Wh B-tiles in LDS, PV + l via MFMA

typedef __attribute__((ext_vector_type(8))) short short8;   // 8 bf16 (4 VGPRs)
typedef __attribute__((ext_vector_type(4))) float floatx4;  // MFMA C/D

union Frag { short8 s8; uint4 u4; };

__device__ inline unsigned as_u(float f) { union { float f; unsigned u; } v; v.f = f; return v.u; }
__device__ inline float as_f(unsigned u) { union { unsigned u; float f; } v; v.u = u; return v.f; }

// RNE pack two fp32 -> bf16x2 (lo = a, hi = b)
__device__ inline unsigned pk_rne(float a, float b) {
  unsigned ua = as_u(a); ua = ua + 0x7fffu + ((ua >> 16) & 1u);
  unsigned ub = as_u(b); ub = ub + 0x7fffu + ((ub >> 16) & 1u);
  return (ua >> 16) | (ub & 0xffff0000u);
}
__device__ inline unsigned short f2bf(float f) {
  unsigned u = as_u(f); u = u + 0x7fffu + ((u >> 16) & 1u);
  return (unsigned short)(u >> 16);
}

// ---------------- conv_w: transpose W (768x512 fp32) -> WbT (512x768 bf16)
__global__ __launch_bounds__(256) void conv_w(const float* __restrict__ W,
                                              unsigned short* __restrict__ WbT) {
  __shared__ unsigned short tile[64][72];  // [n][k], stride 144B (bank-friendly)
  int kt = blockIdx.x >> 3, nt = blockIdx.x & 7;
  int k0 = kt * 64, n0 = nt * 64;
  int t = threadIdx.x;
  int kr = t >> 2, cs = (t & 3) * 16;
#pragma unroll
  for (int q = 0; q < 4; q++) {
    float4 v = *(const float4*)&W[(k0 + kr) * 512 + n0 + cs + q * 4];
    tile[cs + q * 4 + 0][kr] = f2bf(v.x);
    tile[cs + q * 4 + 1][kr] = f2bf(v.y);
    tile[cs + q * 4 + 2][kr] = f2bf(v.z);
    tile[cs + q * 4 + 3][kr] = f2bf(v.w);
  }
  __syncthreads();
  int nr = t >> 2, ks = (t & 3) * 16;
  uint4 d0 = *(const uint4*)&tile[nr][ks];
  uint4 d1 = *(const uint4*)&tile[nr][ks + 8];
  *(uint4*)&WbT[(n0 + nr) * 768 + k0 + ks] = d0;
  *(uint4*)&WbT[(n0 + nr) * 768 + k0 + ks + 8] = d1;
}

// ---------------- gemm_xw: Wh = X @ W, bf16 MFMA, output transposed bf16 WhT[bh*64+f][s]
// tile 128(M) x 64(N), BK=32, grid (8, 64), 256 thr (4 waves, wave tile 64x32).
// Global loads for iter k+1 issued before iter k's MFMA phase (latency hidden).
// LDS rows padded to 80 B (20 banks): 16-B frag blocks spread, 2-way max aliasing.
__global__ __launch_bounds__(256) void gemm_xw(const float* __restrict__ X,
                                               const unsigned short* __restrict__ WbT,
                                               unsigned short* __restrict__ WhT) {
  const int LDA = 40;                       // shorts per LDS row (80 B)
  __shared__ unsigned short Asm[128 * 40];  // [m][k] bf16
  __shared__ unsigned short Bsm[64 * 40];   // [n][k] bf16
  int t = threadIdx.x, w = t >> 6, lane = t & 63;
  int quad = lane >> 4, l15 = lane & 15;
  int m0 = blockIdx.y * 128, n0 = blockIdx.x * 64;
  int wm = (w & 1) * 64, wn = (w >> 1) * 32;

  floatx4 acc[4][2];
#pragma unroll
  for (int mt = 0; mt < 4; mt++)
#pragma unroll
    for (int nt = 0; nt < 2; nt++)
#pragma unroll
      for (int r = 0; r < 4; r++) acc[mt][nt][r] = 0.f;

  int ar = t >> 1, aks = (t & 1) * 16;  // A staging: row 0..127, float-offset {0,16}
  int bn = t >> 2, bks = (t & 3) * 8;   // B staging: n 0..63, short-offset {0,8,16,24}

  const float* xbase = &X[(m0 + ar) * 768 + aks];
  const unsigned short* bbase = &WbT[(n0 + bn) * 768 + bks];
  float4 a0 = *(const float4*)&xbase[0];
  float4 a1 = *(const float4*)&xbase[4];
  float4 a2 = *(const float4*)&xbase[8];
  float4 a3 = *(const float4*)&xbase[12];
  uint4 bv = *(const uint4*)&bbase[0];

  for (int kc = 0; kc < 24; kc++) {
    uint4 pa0, pa1;
    pa0.x = pk_rne(a0.x, a0.y); pa0.y = pk_rne(a0.z, a0.w);
    pa0.z = pk_rne(a1.x, a1.y); pa0.w = pk_rne(a1.z, a1.w);
    pa1.x = pk_rne(a2.x, a2.y); pa1.y = pk_rne(a2.z, a2.w);
    pa1.z = pk_rne(a3.x, a3.y); pa1.w = pk_rne(a3.z, a3.w);
    uint4 bcur = bv;
    __syncthreads();
    *(uint4*)&Asm[ar * LDA + aks] = pa0;
    *(uint4*)&Asm[ar * LDA + aks + 8] = pa1;
    *(uint4*)&Bsm[bn * LDA + bks] = bcur;
    if (kc < 23) {  // prefetch next k-tile while this one is consumed
      int k0 = (kc + 1) * 32;
      a0 = *(const float4*)&xbase[k0 + 0];
      a1 = *(const float4*)&xbase[k0 + 4];
      a2 = *(const float4*)&xbase[k0 + 8];
      a3 = *(const float4*)&xbase[k0 + 12];
      bv = *(const uint4*)&bbase[k0];
    }
    __syncthreads();
    Frag fb[2];
#pragma unroll
    for (int nt = 0; nt < 2; nt++)
      fb[nt] = *(const Frag*)&Bsm[(wn + nt * 16 + l15) * LDA + quad * 8];
#pragma unroll
    for (int mt = 0; mt < 4; mt++) {
      Frag fa = *(const Frag*)&Asm[(wm + mt * 16 + l15) * LDA + quad * 8];
#pragma unroll
      for (int nt = 0; nt < 2; nt++)
        acc[mt][nt] = __builtin_amdgcn_mfma_f32_16x16x32_bf16(fa.s8, fb[nt].s8, acc[mt][nt], 0, 0, 0);
    }
  }
  // epilogue: D row = quad*4+r (m), col = l15 (n); store 4 consecutive s as bf16x4 (8B)
#pragma unroll
  for (int mt = 0; mt < 4; mt++) {
#pragma unroll
    for (int nt = 0; nt < 2; nt++) {
      int n = n0 + wn + nt * 16 + l15;
      int h = n >> 6, f = n & 63;
      int m = m0 + wm + mt * 16 + quad * 4;
      int b = m >> 10, s = m & 1023;
      floatx4 c = acc[mt][nt];
      uint2 st;
      st.x = pk_rne(c[0], c[1]);
      st.y = pk_rne(c[2], c[3]);
      *(uint2*)&WhT[((b * 8 + h) * 64 + f) * 1024 + s] = st;
    }
  }
}

// ---------------- src_dst: srcT/dstT[bh][s] = sum_f WhT[bh][f][s] * a_{src,dst}[f]
// Mask folded into dstT: masked j -> -1e30 -> exp gives exactly 0 in gat_attn.
__global__ __launch_bounds__(256) void src_dst(const unsigned short* __restrict__ WhT,
                                               const float* __restrict__ a,
                                               const int* __restrict__ mask,
                                               float* __restrict__ srcT,
                                               float* __restrict__ dstT) {
  int bh = blockIdx.x >> 1;
  int s2 = (blockIdx.x & 1) * 512 + threadIdx.x * 2;
  const unsigned short* base = &WhT[bh * 64 * 1024 + s2];
  float s0 = 0.f, s1 = 0.f, d0 = 0.f, d1 = 0.f;
#pragma unroll 8
  for (int f = 0; f < 64; f++) {
    unsigned uu = *(const unsigned*)&base[f * 1024];
    float x0 = as_f(uu << 16);
    float x1 = as_f(uu & 0xffff0000u);
    float af = a[f], ad = a[64 + f];
    s0 = fmaf(x0, af, s0); s1 = fmaf(x1, af, s1);
    d0 = fmaf(x0, ad, d0); d1 = fmaf(x1, ad, d1);
  }
  int b = bh >> 3;
  int2 mk = *(const int2*)&mask[b * 1024 + s2];
  float2 sv = {s0, s1};
  float2 dv = {mk.x ? d0 : -1e30f, mk.y ? d1 : -1e30f};
  *(float2*)&srcT[bh * 1024 + s2] = sv;
  *(float2*)&dstT[bh * 1024 + s2] = dv;
}

// ---------------- gat_attn: scores -> A-frags in registers, Wh tile in LDS, PV via MFMA
// grid (16, 64) = (i-tiles of 64, bh), 128 thr = 2 waves -> 1024 blocks, 4 blocks/CU.
// Wave: 32 rows (2 m-tiles). l computed on the MFMA pipe with a ones B-frag:
// lacc[mt][r] = sum_j p_bf16 lands in the same C-rows as acc -> no shuffles at all.
// No mask ops in-loop (folded into dstT); no max-subtraction (|e|<~1, exp can't overflow).
__global__ __launch_bounds__(128) void gat_attn(const unsigned short* __restrict__ WhT,
                                                const float* __restrict__ srcT,
                                                const float* __restrict__ dstT,
                                                float* __restrict__ out) {
  __shared__ unsigned short Bs[64 * 64];  // [f][j] bf16, 16B blocks swizzled: pb = kb ^ (f&7)
  int t = threadIdx.x, w = t >> 6, lane = t & 63;
  int quad = lane >> 4, l15 = lane & 15;
  int bh = blockIdx.y, b = bh >> 3;
  int i0 = blockIdx.x * 64;
  int iw = i0 + w * 32;

  floatx4 acc[2][4], lacc[2];
#pragma unroll
  for (int mt = 0; mt < 2; mt++) {
#pragma unroll
    for (int r = 0; r < 4; r++) lacc[mt][r] = 0.f;
#pragma unroll
    for (int ft = 0; ft < 4; ft++)
#pragma unroll
      for (int r = 0; r < 4; r++) acc[mt][ft][r] = 0.f;
  }
  float src_r[2];
#pragma unroll
  for (int mt = 0; mt < 2; mt++) src_r[mt] = srcT[bh * 1024 + iw + mt * 16 + l15];

  Frag ones;
  ones.u4.x = 0x3F803F80u; ones.u4.y = 0x3F803F80u;
  ones.u4.z = 0x3F803F80u; ones.u4.w = 0x3F803F80u;

  const unsigned short* Wg = WhT + bh * 64 * 1024;
  int sf0 = t >> 3, skb = t & 7;  // staging: f row (0..15, x4 strided), 16B block idx

  for (int j0 = 0; j0 < 1024; j0 += 64) {
    // 1) global loads for the Wh tile (64 f x 64 j bf16 = 8KB), 4 rows per thread
    uint4 g[4];
#pragma unroll
    for (int r = 0; r < 4; r++)
      g[r] = *(const uint4*)&Wg[(sf0 + 16 * r) * 1024 + j0 + skb * 8];
    // 2) scores -> A-fragments (pure VALU, hides the VMEM latency)
    Frag fragA[2][2];
#pragma unroll
    for (int jc = 0; jc < 2; jc++) {
      int jb = j0 + jc * 32 + quad * 8;
      float4 dv0 = *(const float4*)&dstT[bh * 1024 + jb];
      float4 dv1 = *(const float4*)&dstT[bh * 1024 + jb + 4];
      float dj[8] = {dv0.x, dv0.y, dv0.z, dv0.w, dv1.x, dv1.y, dv1.z, dv1.w};
#pragma unroll
      for (int mt = 0; mt < 2; mt++) {
        unsigned pw[4];
#pragma unroll
        for (int pr = 0; pr < 4; pr++) {
          float x0 = src_r[mt] + dj[pr * 2];
          float x1 = src_r[mt] + dj[pr * 2 + 1];
          x0 = fmaxf(x0, 0.2f * x0);  // leaky_relu (alpha<1)
          x1 = fmaxf(x1, 0.2f * x1);
          float p0 = __expf(x0), p1 = __expf(x1);
          pw[pr] = (as_u(p0) >> 16) | (as_u(p1) & 0xffff0000u);  // truncate to bf16x2
        }
        fragA[mt][jc].u4.x = pw[0];
        fragA[mt][jc].u4.y = pw[1];
        fragA[mt][jc].u4.z = pw[2];
        fragA[mt][jc].u4.w = pw[3];
      }
    }
    // 3) stage tile (swizzled)
    __syncthreads();
#pragma unroll
    for (int r = 0; r < 4; r++)
      *(uint4*)&Bs[(sf0 + 16 * r) * 64 + (skb ^ (sf0 & 7)) * 8] = g[r];
    __syncthreads();
    // 4) MFMA: acc[mt][ft] += P(16x32) x Wh(32x16) ; lacc[mt] += P x ones
#pragma unroll
    for (int jc = 0; jc < 2; jc++) {
      Frag fbr[4];
#pragma unroll
      for (int ft = 0; ft < 4; ft++) {
        int f = ft * 16 + l15;
        int kb = jc * 4 + quad;
        fbr[ft] = *(const Frag*)&Bs[f * 64 + (kb ^ (f & 7)) * 8];
      }
#pragma unroll
      for (int mt = 0; mt < 2; mt++) {
#pragma unroll
        for (int ft = 0; ft < 4; ft++)
          acc[mt][ft] = __builtin_amdgcn_mfma_f32_16x16x32_bf16(fragA[mt][jc].s8, fbr[ft].s8,
                                                                acc[mt][ft], 0, 0, 0);
        lacc[mt] = __builtin_amdgcn_mfma_f32_16x16x32_bf16(fragA[mt][jc].s8, ones.s8,
                                                           lacc[mt], 0, 0, 0);
      }
    }
  }
  // epilogue: lacc rows == acc rows (C layout row = quad*4+r), no reduction needed
#pragma unroll
  for (int mt = 0; mt < 2; mt++) {
    float inv[4] = {1.f / lacc[mt][0], 1.f / lacc[mt][1],
                    1.f / lacc[mt][2], 1.f / lacc[mt][3]};
    int mrow = b * 1024 + iw + mt * 16 + quad * 4;
#pragma unroll
    for (int ft = 0; ft < 4; ft++) {
      int col = (bh & 7) * 64 + ft * 16 + l15;
#pragma unroll
      for (int r = 0; r < 4; r++)
        out[(mrow + r) * 512 + col] = acc[mt][ft][r] * inv[r];
    }
  }
}

extern "C" void kernel_launch(void* const* d_in, const int* in_sizes, int n_in,
                              void* d_out, int out_size, void* d_ws, size_t ws_size,
                              hipStream_t stream) {
  const float* X = (const float*)d_in[0];   // (8,1024,768)
  const int* mask = (const int*)d_in[1];    // (8,1024)
  const float* W = (const float*)d_in[2];   // (768,512)
  const float* a = (const float*)d_in[3];   // (128,)
  float* out = (float*)d_out;               // (8,1024,512)

  char* ws = (char*)d_ws;
  unsigned short* WhT = (unsigned short*)ws;                    // 64*64*1024 bf16 = 8388608 B
  unsigned short* WbT = (unsigned short*)(ws + 8388608);        // 512*768 bf16  = 786432 B
  float* srcT = (float*)(ws + 9175040);                         // 64*1024 f32   = 262144 B
  float* dstT = (float*)(ws + 9437184);                         // 64*1024 f32

  conv_w<<<96, 256, 0, stream>>>(W, WbT);
  gemm_xw<<<dim3(8, 64), 256, 0, stream>>>(X, WbT, WhT);
  src_dst<<<128, 256, 0, stream>>>(WhT, a, mask, srcT, dstT);
  gat_attn<<<dim3(16, 64), 128, 0, stream>>>(WhT, srcT, dstT, out);
}